// Round 4
// baseline (177.463 us; speedup 1.0000x reference)
//
#include <hip/hip_runtime.h>
#include <hip/hip_bf16.h>
#include <stdint.h>

// ---------------------------------------------------------------------------
// Net_71373766525077: SNN leaky layer.
//   cur = x @ W^T   (1024x4096 @ 4096x4096 fp32; mem tol 7.92 -> bf16 MFMA)
//   scan t: reset=(mem>1); mem=0.9*mem+cur[t]-reset; spk=(mem>1)
//   out = concat(spk_rec[T][N], mem_rec[T][N]) fp32
//
// R15 -> R16: RESUBMIT of R15 unchanged (R15 bench died to a container
// acquisition failure, not a kernel verdict; audit found no hang/fault
// candidate: XCD decode bijective, barriers non-divergent, all vector
// accesses aligned). R15 rationale:
//  (1) gemm: bijective XCD swizzle (S=4: xcd = 2*z + nHi). Default round-
//      robin mixed all 4 split-K z-slices per XCD (24 L2 streams, mixed K
//      offsets, A-sharers split across XCDs) -> staged loads miss L2 and the
//      3-phase vmcnt cover (~800cy) < L3/HBM latency. Now one z per XCD
//      pair: 4 A-panels (8x shared) + 8 B-panels (4x shared), same K phase.
//  (2) scan: NB_N 16->8, 256 thr -> 512 blocks = 2/CU. R14 scan (~28us vs
//      ~11us BW floor) was phase-latency-bound with 1 block/CU; two
//      independent phase pipelines per CU now overlap stage-load latency
//      and the consumer's serial chain.
// Ledger R14: fills 81 (harness) + cvt 19 (BW floor) + gemm 41.7 + scan ~28.
// Predicted: gemm ~38, scan ~17, total ~153.
// ---------------------------------------------------------------------------

typedef __attribute__((ext_vector_type(8))) short bf16x8;
typedef __attribute__((ext_vector_type(4))) float floatx4;

#define T_STEPS 1024
#define N_IN    4096
#define N_OUT   4096

#define PH_T 128                  // timesteps per scan phase
#define NPH  (T_STEPS / PH_T)     // 8 phases
#define NB_N 8                    // neurons per scan block
#define TP   132                  // LDS t-stride (floats, 16B-aligned rows)

#define TN ((size_t)T_STEPS * N_OUT)

__device__ __forceinline__ unsigned short f2bf_rne(float f) {
    unsigned int u = __builtin_bit_cast(unsigned int, f);
    unsigned int r = 0x7FFFu + ((u >> 16) & 1u);
    return (unsigned short)((u + r) >> 16);
}

// One kernel converts both inputs (x then W), float4/ushort4 vectorized.
__global__ __launch_bounds__(256) void cvt2_kernel(const float4* __restrict__ inX,
                                                   ushort4* __restrict__ outX, int n4x,
                                                   const float4* __restrict__ inW,
                                                   ushort4* __restrict__ outW, int n4w) {
    int i = blockIdx.x * blockDim.x + threadIdx.x;
    const float4* in;
    ushort4* out;
    int k;
    if (i < n4x) { in = inX; out = outX; k = i; }
    else         { in = inW; out = outW; k = i - n4x; if (k >= n4w) return; }
    float4 v = in[k];
    ushort4 o;
    o.x = f2bf_rne(v.x);
    o.y = f2bf_rne(v.y);
    o.z = f2bf_rne(v.z);
    o.w = f2bf_rne(v.w);
    out[k] = o;
}

__device__ __forceinline__ void gload16(const void* g, void* l) {
    __builtin_amdgcn_global_load_lds((const __attribute__((address_space(1))) void*)g,
                                     (__attribute__((address_space(3))) void*)l,
                                     16, 0, 0);
}

#define SB0()  __builtin_amdgcn_sched_barrier(0)
#define BARR() __builtin_amdgcn_s_barrier()

// ---------------------------------------------------------------------------
// 8-phase 256x256 GEMM, Pb[z][N][T] = (A[M][kz] * B[N][kz]^T)^T, bf16 in/out.
// grid = 64*S blocks x 512 thr. S=4: XCD-packed decode (one z per XCD pair,
// n-halves split): xcd=bid&7, k=bid>>3; z=xcd>>1, n=(xcd&1)*8+(k>>2), m=k&3.
// 8 waves 2Mx4N, per-wave C = 128x64 (acc[8][4] of 16x16 frags).
// LDS 128KB: A@[b*16384], B@[32768+b*16384], each 256 rows x 64 bf16.
// Swizzled element layout: LDS(row, col ^ ((row&7)<<3)); staged via linear
// global_load_lds with source col pre-permuted ((lane&7)^(lane>>3))<<3.
// Phase schedule per iteration i (tiles t0=2i from buf0, t1=2i+1 from buf1):
//   p0: rd A0q0+B0q0, st buf1.Ah0(t1)   p4: rd A1q0+B1q0, st buf0.Ah0(t2)
//   p1: rd B0q1,      st buf1.Ah1(t1)   p5: rd B1q1,      st buf0.Ah1(t2)
//   p2: rd A0q1,      st buf0.Bh0(t2)   p6: rd A1q1,      st buf1.Bh0(t3)
//   p3: -,            st buf0.Bh1(t2)   p7: -,            st buf1.Bh1(t3)
//   vmcnt(4) at end of p3 (retires buf1 A+prev B) and p7 (retires buf0 A+B).
// Epilogue: acc frag regs are 4 consecutive t for one n -> pack 4 bf16 and
// global_store_dwordx2 into n-major Pb.
// ---------------------------------------------------------------------------
__global__ __launch_bounds__(512, 2) void gemm8(const short* __restrict__ A,
                                                const short* __restrict__ B,
                                                unsigned short* __restrict__ Pb,
                                                int kLen) {
    __shared__ short lds[65536];  // 128 KB

    const int tid  = threadIdx.x;
    const int lane = tid & 63;
    const int wv   = tid >> 6;          // 0..7
    const int wm   = (wv >> 2) * 128;   // M-wave offset: 0 / 128
    const int wn   = (wv & 3) * 64;     // N-wave offset: 0/64/128/192

    const int bid = blockIdx.x;
    int z, mT, nT;
    if (gridDim.x == 256) {
        // S=4 XCD-packed: blockIdx -> XCD is bid%8 (round-robin heuristic).
        const int xcd = bid & 7;
        const int k   = bid >> 3;
        z  = xcd >> 1;
        mT = k & 3;
        nT = (xcd & 1) * 8 + (k >> 2);
    } else {
        z  = bid >> 6;
        mT = (bid >> 4) & 3;
        nT = bid & 15;
    }
    const long bm  = (long)mT * 256;
    const long bn  = (long)nT * 256;
    const int kBeg = z * kLen;
    unsigned short* __restrict__ Pz = Pb + (size_t)z * TN;
    const int NT    = kLen / 64;   // K-tiles of 64
    const int NITER = NT / 2;      // 2 K-tiles per iteration

    // staging source geometry: lane covers row (lane>>3), 16B slot (lane&7);
    // source col block pre-permuted so linear LDS ends up XOR-swizzled.
    const int srow = lane >> 3;                     // 0..7
    const int scol = ((lane & 7) ^ srow) << 3;      // inverse-swizzled col
    const short* aSrc = A + (bm + wv * 8 + srow) * (long)N_IN + kBeg + scol;
    const short* bSrc = B + (bn + wv * 8 + srow) * (long)N_IN + kBeg + scol;
    const int ldA = wv * 512;            // + b*16384 + h*8192 + q*4096 (shorts)
    const int ldB = 32768 + wv * 512;

    // fragment read geometry (16x16x32 MFMA), swizzle applied on read
    const int fm    = lane & 15;
    const int fko   = (lane >> 4) * 8;
    const int cbase = fko ^ ((fm & 7) << 3);

    floatx4 acc[8][4] = {};
    bf16x8 af[4][2];      // A frags of current qm: [mi][ks]
    bf16x8 bq[2][2][2];   // B frags both qn: [qn][nj][ks]

    auto loadA = [&](int b, int qm) {
#pragma unroll
        for (int mi = 0; mi < 4; ++mi)
#pragma unroll
            for (int ks = 0; ks < 2; ++ks)
                af[mi][ks] = *(const bf16x8*)(
                    lds + b * 16384 + (wm + qm * 64 + mi * 16 + fm) * 64 +
                    (cbase ^ (ks << 5)));
    };
    auto loadB = [&](int b, int qn) {
#pragma unroll
        for (int nj = 0; nj < 2; ++nj)
#pragma unroll
            for (int ks = 0; ks < 2; ++ks)
                bq[qn][nj][ks] = *(const bf16x8*)(
                    lds + 32768 + b * 16384 + (wn + qn * 32 + nj * 16 + fm) * 64 +
                    (cbase ^ (ks << 5)));
    };
    auto mfma16 = [&](int qm, int qn) {
        __builtin_amdgcn_s_setprio(1);
#pragma unroll
        for (int ks = 0; ks < 2; ++ks)
#pragma unroll
            for (int mi = 0; mi < 4; ++mi)
#pragma unroll
                for (int nj = 0; nj < 2; ++nj)
                    acc[qm * 4 + mi][qn * 2 + nj] =
                        __builtin_amdgcn_mfma_f32_16x16x32_bf16(
                            af[mi][ks], bq[qn][nj][ks],
                            acc[qm * 4 + mi][qn * 2 + nj], 0, 0, 0);
        __builtin_amdgcn_s_setprio(0);
    };
    // one half-operand = 128 rows x 64 bf16 = 2 gload rounds (q=0,1)
    auto stageA = [&](int b, int h, int t) {
        const short* s = aSrc + (size_t)(h * 128) * N_IN + t * 64;
        gload16(s,                    lds + b * 16384 + h * 8192 + ldA);
        gload16(s + (size_t)64 * N_IN, lds + b * 16384 + h * 8192 + 4096 + ldA);
    };
    auto stageB = [&](int b, int h, int t) {
        const short* s = bSrc + (size_t)(h * 128) * N_IN + t * 64;
        gload16(s,                    lds + b * 16384 + h * 8192 + ldB);
        gload16(s + (size_t)64 * N_IN, lds + b * 16384 + h * 8192 + 4096 + ldB);
    };

    // ---- prologue: full tile0 -> buf0, tile1 B-halves -> buf1 (12 loads) ----
    stageA(0, 0, 0); stageA(0, 1, 0);
    stageB(0, 0, 0); stageB(0, 1, 0);
    stageB(1, 0, 1); stageB(1, 1, 1);
    asm volatile("s_waitcnt vmcnt(4)" ::: "memory");  // buf0 landed; buf1.B in flight
    SB0();
    BARR();

    for (int i = 0; i < NITER; ++i) {
        const int t1 = 2 * i + 1;
        const int t2 = 2 * i + 2;
        const int t3 = 2 * i + 3;
        const bool more = (i + 1 < NITER);

        // ---- p0: buf0 quadrant (qm0,qn0) ----
        loadA(0, 0); loadB(0, 0);
        stageA(1, 0, t1);
        asm volatile("s_waitcnt lgkmcnt(8)" ::: "memory");
        SB0(); BARR();
        asm volatile("s_waitcnt lgkmcnt(0)" ::: "memory"); SB0();
        mfma16(0, 0);
        SB0(); BARR();

        // ---- p1: buf0 (qm0,qn1) ----
        loadB(0, 1);
        stageA(1, 1, t1);
        SB0(); BARR();
        asm volatile("s_waitcnt lgkmcnt(0)" ::: "memory"); SB0();
        mfma16(0, 1);
        SB0(); BARR();

        // ---- p2: buf0 (qm1,qn0) ----
        loadA(0, 1);
        if (more) stageB(0, 0, t2);
        SB0(); BARR();
        asm volatile("s_waitcnt lgkmcnt(0)" ::: "memory"); SB0();
        mfma16(1, 0);
        SB0(); BARR();

        // ---- p3: buf0 (qm1,qn1); retire buf1 stages ----
        if (more) stageB(0, 1, t2);
        SB0(); BARR();
        mfma16(1, 1);
        if (more) { asm volatile("s_waitcnt vmcnt(4)" ::: "memory"); }
        else      { asm volatile("s_waitcnt vmcnt(0)" ::: "memory"); }
        SB0(); BARR();

        // ---- p4: buf1 (qm0,qn0) ----
        loadA(1, 0); loadB(1, 0);
        if (more) stageA(0, 0, t2);
        asm volatile("s_waitcnt lgkmcnt(8)" ::: "memory");
        SB0(); BARR();
        asm volatile("s_waitcnt lgkmcnt(0)" ::: "memory"); SB0();
        mfma16(0, 0);
        SB0(); BARR();

        // ---- p5: buf1 (qm0,qn1) ----
        loadB(1, 1);
        if (more) stageA(0, 1, t2);
        SB0(); BARR();
        asm volatile("s_waitcnt lgkmcnt(0)" ::: "memory"); SB0();
        mfma16(0, 1);
        SB0(); BARR();

        // ---- p6: buf1 (qm1,qn0) ----
        loadA(1, 1);
        if (more) stageB(1, 0, t3);
        SB0(); BARR();
        asm volatile("s_waitcnt lgkmcnt(0)" ::: "memory"); SB0();
        mfma16(1, 0);
        SB0(); BARR();

        // ---- p7: buf1 (qm1,qn1); retire buf0 stages ----
        if (more) stageB(1, 1, t3);
        SB0(); BARR();
        mfma16(1, 1);
        if (more) { asm volatile("s_waitcnt vmcnt(4)" ::: "memory"); }
        SB0(); BARR();
    }

    // C/D layout: col(n)=lane&15, row(m=t)=(lane>>4)*4+reg [m89/m91].
    // n-major Pb: 4 regs = 4 consecutive t -> one dwordx2 store per frag.
    const int cn = lane & 15;
    const int cm = (lane >> 4) * 4;
#pragma unroll
    for (int mi = 0; mi < 8; ++mi)
#pragma unroll
        for (int nj = 0; nj < 4; ++nj) {
            unsigned int lo = (unsigned int)f2bf_rne(acc[mi][nj][0]) |
                              ((unsigned int)f2bf_rne(acc[mi][nj][1]) << 16);
            unsigned int hi = (unsigned int)f2bf_rne(acc[mi][nj][2]) |
                              ((unsigned int)f2bf_rne(acc[mi][nj][3]) << 16);
            uint2 v; v.x = lo; v.y = hi;
            size_t nIdx = (size_t)(bn + wn + nj * 16 + cn);
            *(uint2*)(Pz + nIdx * T_STEPS + (size_t)(bm + wm + mi * 16 + cm)) = v;
        }
}

// Fused scan over n-major Pb[z][N][T]: 512 blocks x 256 threads (2 blocks/CU
// for cross-block latency overlap); block owns NB_N=8 neurons for ALL t.
// Waves 0-2 (producers): write out phase ph-1 spk/mem from ringMem (float4
// stores, 2 per t); threads 0-127 additionally stage phase ph+1: thread owns
// (n, 8-t chunk) -> uint4 load per partial, f32-sum, 2x float4 ring writes.
// Wave 3 (consumer, lanes 0..7): serial recurrence ringCur -> ringMem.
template <int NPART>
__global__ __launch_bounds__(256) void scan_kernel(const unsigned short* __restrict__ Pb,
                                                   float* __restrict__ out) {
    __shared__ float ringCur[2][NB_N * TP];   // 8.4 KB
    __shared__ float ringMem[2][NB_N * TP];   // 8.4 KB

    const int tid  = threadIdx.x;
    const int wv   = tid >> 6;     // 0..3
    const int lane = tid & 63;
    const int n0   = blockIdx.x * NB_N;

    const int pn = lane & 7;    // consumer: neuron offset within block

    // staging geometry (threads 0-127)
    const int sn = tid >> 4;    // neuron 0..7
    const int sc = tid & 15;    // 8-t chunk 0..15

    float mem = 0.0f;           // consumer state (wave 3, lanes 0..7)

    auto stage = [&](int buf, size_t tb) {
        float s[8];
#pragma unroll
        for (int j = 0; j < 8; ++j) s[j] = 0.0f;
#pragma unroll
        for (int zz = 0; zz < NPART; ++zz) {
            const uint4 v = *(const uint4*)(Pb + (size_t)zz * TN +
                                            (size_t)(n0 + sn) * T_STEPS + tb + sc * 8);
            unsigned int w0 = v.x, w1 = v.y, w2 = v.z, w3 = v.w;
            s[0] += __builtin_bit_cast(float, w0 << 16);
            s[1] += __builtin_bit_cast(float, w0 & 0xFFFF0000u);
            s[2] += __builtin_bit_cast(float, w1 << 16);
            s[3] += __builtin_bit_cast(float, w1 & 0xFFFF0000u);
            s[4] += __builtin_bit_cast(float, w2 << 16);
            s[5] += __builtin_bit_cast(float, w2 & 0xFFFF0000u);
            s[6] += __builtin_bit_cast(float, w3 << 16);
            s[7] += __builtin_bit_cast(float, w3 & 0xFFFF0000u);
        }
        float4 f0; f0.x = s[0]; f0.y = s[1]; f0.z = s[2]; f0.w = s[3];
        float4 f1; f1.x = s[4]; f1.y = s[5]; f1.z = s[6]; f1.w = s[7];
        float* rc = &ringCur[buf][sn * TP + sc * 8];
        *(float4*)rc = f0;
        *(float4*)(rc + 4) = f1;
    };

    auto writeOut = [&](int buf, size_t tb) {
        const float* mr = ringMem[buf];
        for (int it = tid; it < 256; it += 192) {
            int t = it >> 1;
            int h = it & 1;
            float m0 = mr[(h * 4 + 0) * TP + t];
            float m1 = mr[(h * 4 + 1) * TP + t];
            float m2 = mr[(h * 4 + 2) * TP + t];
            float m3 = mr[(h * 4 + 3) * TP + t];
            float4 mv; mv.x = m0; mv.y = m1; mv.z = m2; mv.w = m3;
            float4 sv;
            sv.x = m0 > 1.0f ? 1.0f : 0.0f;
            sv.y = m1 > 1.0f ? 1.0f : 0.0f;
            sv.z = m2 > 1.0f ? 1.0f : 0.0f;
            sv.w = m3 > 1.0f ? 1.0f : 0.0f;
            size_t idx = (tb + t) * N_OUT + n0 + h * 4;
            *(float4*)&out[idx]      = sv;
            *(float4*)&out[TN + idx] = mv;
        }
    };

    // ---- prefill: phase 0 -> ringCur[0] ----
    if (tid < 128) stage(0, 0);
    __syncthreads();

    for (int ph = 0; ph < NPH; ++ph) {
        if (wv < 3) {
            if (ph >= 1) writeOut((ph - 1) & 1, (size_t)(ph - 1) * PH_T);
            if (tid < 128 && ph + 1 < NPH)
                stage((ph + 1) & 1, (size_t)(ph + 1) * PH_T);
        } else if (lane < 8) {
            // consumer: 128 serial steps out of ringCur[ph&1]
            const float* base = &ringCur[ph & 1][pn * TP];
            float* mbase = &ringMem[ph & 1][pn * TP];
#pragma unroll
            for (int sub = 0; sub < 4; ++sub) {
                float2 buf[16];
#pragma unroll
                for (int q = 0; q < 16; ++q)
                    buf[q] = *(const float2*)&base[sub * 32 + q * 2];
#pragma unroll
                for (int q = 0; q < 16; ++q) {
                    float rst = mem > 1.0f ? 1.0f : 0.0f;
                    mem = fmaf(0.9f, mem, buf[q].x) - rst;
                    float m0 = mem;
                    rst = mem > 1.0f ? 1.0f : 0.0f;
                    mem = fmaf(0.9f, mem, buf[q].y) - rst;
                    float2 mo; mo.x = m0; mo.y = mem;
                    *(float2*)&mbase[sub * 32 + q * 2] = mo;
                }
            }
        }
        __syncthreads();
    }

    // ---- tail: write out phase NPH-1 ----
    if (wv < 3) writeOut((NPH - 1) & 1, (size_t)(NPH - 1) * PH_T);
}

extern "C" void kernel_launch(void* const* d_in, const int* in_sizes, int n_in,
                              void* d_out, int out_size, void* d_ws, size_t ws_size,
                              hipStream_t stream) {
    const float* x = (const float*)d_in[0];  // [1024][4096] fp32
    const float* W = (const float*)d_in[1];  // [4096][4096] fp32
    float* out = (float*)d_out;              // [2][1024][4096] fp32

    char* ws = (char*)d_ws;
    const size_t xbBytes = (size_t)T_STEPS * N_IN * 2;    // 8 MB
    const size_t WbBytes = (size_t)N_OUT * N_IN * 2;      // 33.6 MB
    const size_t PBytes  = TN * 2;                        // 8.4 MB per bf16 partial
    short* xb = (short*)ws;
    short* Wb = (short*)(ws + xbBytes);
    unsigned short* Pb = (unsigned short*)(ws + xbBytes + WbBytes);

    // Split-K: S=4 -> 256 blocks = 1/CU for the 128KB-LDS 8-phase gemm.
    int S = 1;
    if (ws_size >= xbBytes + WbBytes + 4 * PBytes)      S = 4;
    else if (ws_size >= xbBytes + WbBytes + 2 * PBytes) S = 2;

    {
        const int n4x = T_STEPS * N_IN / 4;
        const int n4w = N_OUT * N_IN / 4;
        const int nthr = n4x + n4w;
        cvt2_kernel<<<(nthr + 255) / 256, 256, 0, stream>>>(
            (const float4*)x, (ushort4*)xb, n4x,
            (const float4*)W, (ushort4*)Wb, n4w);
    }

    gemm8<<<64 * S, 512, 0, stream>>>(xb, Wb, Pb, N_IN / S);

    if (S == 4)      scan_kernel<4><<<N_OUT / NB_N, 256, 0, stream>>>(Pb, out);
    else if (S == 2) scan_kernel<2><<<N_OUT / NB_N, 256, 0, stream>>>(Pb, out);
    else             scan_kernel<1><<<N_OUT / NB_N, 256, 0, stream>>>(Pb, out);
}

// Round 5
// 168.801 us; speedup vs baseline: 1.0513x; 1.0513x over previous
//
#include <hip/hip_runtime.h>
#include <hip/hip_bf16.h>
#include <stdint.h>

// ---------------------------------------------------------------------------
// Net_71373766525077: SNN leaky layer.
//   cur = x @ W^T   (1024x4096 @ 4096x4096 fp32; mem tol 7.92 -> bf16 MFMA)
//   scan t: reset=(mem>1); mem=0.9*mem+cur[t]-reset; spk=(mem>1)
//   out = concat(spk_rec[T][N], mem_rec[T][N]) fp32
//
// R16 -> R17: revert both R15/R16 regressions + one new gemm lever.
//  (1) gemm decode: back to linear (R13: 40.1us vs packed 42.2; FETCH halved
//      but time rose -> staged-fetch locality is not the limiter).
//  (2) scan: back to R14 exact (NB_N=16, 512thr, 256 blocks; residual 27.9
//      vs NB_N=8's 35.3 - 32B out-row chunks fragmented HBM writes).
//  (3) NEW: epilogue spread. Phase arithmetic: steady phase ~1440cy vs
//      m201-level ~1000cy; deficit is fixed cost over NITER=8, mostly the
//      synchronized 33.6MB store burst after the K-loop (~5us MFMA-idle
//      tail, Occupancy 16.5% < structural 25%). Peel the last iteration:
//      quadrant (qm,qn) is final after its p4..p7 mfma16 -> store its 8
//      frags right there, overlapping stores with remaining MFMA phases.
// Ledger: fills 81 (harness) + cvt 19 (BW floor) + gemm 40 + scan ~28.
// Predicted: gemm ~37-38, total ~165-167.
// ---------------------------------------------------------------------------

typedef __attribute__((ext_vector_type(8))) short bf16x8;
typedef __attribute__((ext_vector_type(4))) float floatx4;

#define T_STEPS 1024
#define N_IN    4096
#define N_OUT   4096

#define PH_T 128                  // timesteps per scan phase
#define NPH  (T_STEPS / PH_T)     // 8 phases
#define NB_N 16                   // neurons per scan block
#define TP   132                  // LDS t-stride (floats, 16B-aligned rows)

#define TN ((size_t)T_STEPS * N_OUT)

__device__ __forceinline__ unsigned short f2bf_rne(float f) {
    unsigned int u = __builtin_bit_cast(unsigned int, f);
    unsigned int r = 0x7FFFu + ((u >> 16) & 1u);
    return (unsigned short)((u + r) >> 16);
}

// One kernel converts both inputs (x then W), float4/ushort4 vectorized.
__global__ __launch_bounds__(256) void cvt2_kernel(const float4* __restrict__ inX,
                                                   ushort4* __restrict__ outX, int n4x,
                                                   const float4* __restrict__ inW,
                                                   ushort4* __restrict__ outW, int n4w) {
    int i = blockIdx.x * blockDim.x + threadIdx.x;
    const float4* in;
    ushort4* out;
    int k;
    if (i < n4x) { in = inX; out = outX; k = i; }
    else         { in = inW; out = outW; k = i - n4x; if (k >= n4w) return; }
    float4 v = in[k];
    ushort4 o;
    o.x = f2bf_rne(v.x);
    o.y = f2bf_rne(v.y);
    o.z = f2bf_rne(v.z);
    o.w = f2bf_rne(v.w);
    out[k] = o;
}

__device__ __forceinline__ void gload16(const void* g, void* l) {
    __builtin_amdgcn_global_load_lds((const __attribute__((address_space(1))) void*)g,
                                     (__attribute__((address_space(3))) void*)l,
                                     16, 0, 0);
}

#define SB0()  __builtin_amdgcn_sched_barrier(0)
#define BARR() __builtin_amdgcn_s_barrier()

// ---------------------------------------------------------------------------
// 8-phase 256x256 GEMM, Pb[z][N][T] = (A[M][kz] * B[N][kz]^T)^T, bf16 in/out.
// grid = 64*S blocks x 512 thr; z = bid>>6, m_tile = (bid>>4)&3, n_tile=bid&15.
// 8 waves 2Mx4N, per-wave C = 128x64 (acc[8][4] of 16x16 frags).
// LDS 128KB: A@[b*16384], B@[32768+b*16384], each 256 rows x 64 bf16.
// Swizzled element layout: LDS(row, col ^ ((row&7)<<3)); staged via linear
// global_load_lds with source col pre-permuted ((lane&7)^(lane>>3))<<3.
// Phase schedule per iteration i (tiles t0=2i from buf0, t1=2i+1 from buf1):
//   p0: rd A0q0+B0q0, st buf1.Ah0(t1)   p4: rd A1q0+B1q0, st buf0.Ah0(t2)
//   p1: rd B0q1,      st buf1.Ah1(t1)   p5: rd B1q1,      st buf0.Ah1(t2)
//   p2: rd A0q1,      st buf0.Bh0(t2)   p6: rd A1q1,      st buf1.Bh0(t3)
//   p3: -,            st buf0.Bh1(t2)   p7: -,            st buf1.Bh1(t3)
//   vmcnt(4) at end of p3 (retires buf1 A+prev B) and p7 (retires buf0 A+B).
// Last iteration peeled: no prefetch; quadrant (qm,qn) stored right after
// its final mfma16 at p4..p7 (8 uint2 stores/thread per phase) to overlap
// the Pb store burst with the tail MFMA phases.
// ---------------------------------------------------------------------------
__global__ __launch_bounds__(512, 2) void gemm8(const short* __restrict__ A,
                                                const short* __restrict__ B,
                                                unsigned short* __restrict__ Pb,
                                                int kLen) {
    __shared__ short lds[65536];  // 128 KB

    const int tid  = threadIdx.x;
    const int lane = tid & 63;
    const int wv   = tid >> 6;          // 0..7
    const int wm   = (wv >> 2) * 128;   // M-wave offset: 0 / 128
    const int wn   = (wv & 3) * 64;     // N-wave offset: 0/64/128/192

    const int bid  = blockIdx.x;
    const int z    = bid >> 6;
    const int tile = bid & 63;
    const long bm  = (long)(tile >> 4) * 256;
    const long bn  = (long)(tile & 15) * 256;
    const int kBeg = z * kLen;
    unsigned short* __restrict__ Pz = Pb + (size_t)z * TN;
    const int NT    = kLen / 64;   // K-tiles of 64
    const int NITER = NT / 2;      // 2 K-tiles per iteration

    // staging source geometry: lane covers row (lane>>3), 16B slot (lane&7);
    // source col block pre-permuted so linear LDS ends up XOR-swizzled.
    const int srow = lane >> 3;                     // 0..7
    const int scol = ((lane & 7) ^ srow) << 3;      // inverse-swizzled col
    const short* aSrc = A + (bm + wv * 8 + srow) * (long)N_IN + kBeg + scol;
    const short* bSrc = B + (bn + wv * 8 + srow) * (long)N_IN + kBeg + scol;
    const int ldA = wv * 512;            // + b*16384 + h*8192 + q*4096 (shorts)
    const int ldB = 32768 + wv * 512;

    // fragment read geometry (16x16x32 MFMA), swizzle applied on read
    const int fm    = lane & 15;
    const int fko   = (lane >> 4) * 8;
    const int cbase = fko ^ ((fm & 7) << 3);

    floatx4 acc[8][4] = {};
    bf16x8 af[4][2];      // A frags of current qm: [mi][ks]
    bf16x8 bq[2][2][2];   // B frags both qn: [qn][nj][ks]

    auto loadA = [&](int b, int qm) {
#pragma unroll
        for (int mi = 0; mi < 4; ++mi)
#pragma unroll
            for (int ks = 0; ks < 2; ++ks)
                af[mi][ks] = *(const bf16x8*)(
                    lds + b * 16384 + (wm + qm * 64 + mi * 16 + fm) * 64 +
                    (cbase ^ (ks << 5)));
    };
    auto loadB = [&](int b, int qn) {
#pragma unroll
        for (int nj = 0; nj < 2; ++nj)
#pragma unroll
            for (int ks = 0; ks < 2; ++ks)
                bq[qn][nj][ks] = *(const bf16x8*)(
                    lds + 32768 + b * 16384 + (wn + qn * 32 + nj * 16 + fm) * 64 +
                    (cbase ^ (ks << 5)));
    };
    auto mfma16 = [&](int qm, int qn) {
        __builtin_amdgcn_s_setprio(1);
#pragma unroll
        for (int ks = 0; ks < 2; ++ks)
#pragma unroll
            for (int mi = 0; mi < 4; ++mi)
#pragma unroll
                for (int nj = 0; nj < 2; ++nj)
                    acc[qm * 4 + mi][qn * 2 + nj] =
                        __builtin_amdgcn_mfma_f32_16x16x32_bf16(
                            af[mi][ks], bq[qn][nj][ks],
                            acc[qm * 4 + mi][qn * 2 + nj], 0, 0, 0);
        __builtin_amdgcn_s_setprio(0);
    };
    // one half-operand = 128 rows x 64 bf16 = 2 gload rounds (q=0,1)
    auto stageA = [&](int b, int h, int t) {
        const short* s = aSrc + (size_t)(h * 128) * N_IN + t * 64;
        gload16(s,                    lds + b * 16384 + h * 8192 + ldA);
        gload16(s + (size_t)64 * N_IN, lds + b * 16384 + h * 8192 + 4096 + ldA);
    };
    auto stageB = [&](int b, int h, int t) {
        const short* s = bSrc + (size_t)(h * 128) * N_IN + t * 64;
        gload16(s,                    lds + b * 16384 + h * 8192 + ldB);
        gload16(s + (size_t)64 * N_IN, lds + b * 16384 + h * 8192 + 4096 + ldB);
    };
    // C/D layout: col(n)=lane&15, row(m=t)=(lane>>4)*4+reg [m89/m91].
    // n-major Pb: 4 regs = 4 consecutive t -> one dwordx2 store per frag.
    const int cn = lane & 15;
    const int cm = (lane >> 4) * 4;
    auto storeQuad = [&](int qm, int qn) {
#pragma unroll
        for (int mi = 0; mi < 4; ++mi)
#pragma unroll
            for (int nj = 0; nj < 2; ++nj) {
                const floatx4 a = acc[qm * 4 + mi][qn * 2 + nj];
                unsigned int lo = (unsigned int)f2bf_rne(a[0]) |
                                  ((unsigned int)f2bf_rne(a[1]) << 16);
                unsigned int hi = (unsigned int)f2bf_rne(a[2]) |
                                  ((unsigned int)f2bf_rne(a[3]) << 16);
                uint2 v; v.x = lo; v.y = hi;
                size_t nIdx = (size_t)(bn + wn + qn * 32 + nj * 16 + cn);
                *(uint2*)(Pz + nIdx * T_STEPS +
                          (size_t)(bm + wm + qm * 64 + mi * 16 + cm)) = v;
            }
    };

    // ---- prologue: full tile0 -> buf0, tile1 B-halves -> buf1 (12 loads) ----
    stageA(0, 0, 0); stageA(0, 1, 0);
    stageB(0, 0, 0); stageB(0, 1, 0);
    stageB(1, 0, 1); stageB(1, 1, 1);
    asm volatile("s_waitcnt vmcnt(4)" ::: "memory");  // buf0 landed; buf1.B in flight
    SB0();
    BARR();

    for (int i = 0; i < NITER - 1; ++i) {
        const int t1 = 2 * i + 1;
        const int t2 = 2 * i + 2;
        const int t3 = 2 * i + 3;

        // ---- p0: buf0 quadrant (qm0,qn0) ----
        loadA(0, 0); loadB(0, 0);
        stageA(1, 0, t1);
        asm volatile("s_waitcnt lgkmcnt(8)" ::: "memory");
        SB0(); BARR();
        asm volatile("s_waitcnt lgkmcnt(0)" ::: "memory"); SB0();
        mfma16(0, 0);
        SB0(); BARR();

        // ---- p1: buf0 (qm0,qn1) ----
        loadB(0, 1);
        stageA(1, 1, t1);
        SB0(); BARR();
        asm volatile("s_waitcnt lgkmcnt(0)" ::: "memory"); SB0();
        mfma16(0, 1);
        SB0(); BARR();

        // ---- p2: buf0 (qm1,qn0) ----
        loadA(0, 1);
        stageB(0, 0, t2);
        SB0(); BARR();
        asm volatile("s_waitcnt lgkmcnt(0)" ::: "memory"); SB0();
        mfma16(1, 0);
        SB0(); BARR();

        // ---- p3: buf0 (qm1,qn1); retire buf1 stages ----
        stageB(0, 1, t2);
        SB0(); BARR();
        mfma16(1, 1);
        asm volatile("s_waitcnt vmcnt(4)" ::: "memory");
        SB0(); BARR();

        // ---- p4: buf1 (qm0,qn0) ----
        loadA(1, 0); loadB(1, 0);
        stageA(0, 0, t2);
        asm volatile("s_waitcnt lgkmcnt(8)" ::: "memory");
        SB0(); BARR();
        asm volatile("s_waitcnt lgkmcnt(0)" ::: "memory"); SB0();
        mfma16(0, 0);
        SB0(); BARR();

        // ---- p5: buf1 (qm0,qn1) ----
        loadB(1, 1);
        stageA(0, 1, t2);
        SB0(); BARR();
        asm volatile("s_waitcnt lgkmcnt(0)" ::: "memory"); SB0();
        mfma16(0, 1);
        SB0(); BARR();

        // ---- p6: buf1 (qm1,qn0) ----
        loadA(1, 1);
        stageB(1, 0, t3);
        SB0(); BARR();
        asm volatile("s_waitcnt lgkmcnt(0)" ::: "memory"); SB0();
        mfma16(1, 0);
        SB0(); BARR();

        // ---- p7: buf1 (qm1,qn1); retire buf0 stages ----
        stageB(1, 1, t3);
        SB0(); BARR();
        mfma16(1, 1);
        asm volatile("s_waitcnt vmcnt(4)" ::: "memory");
        SB0(); BARR();
    }

    // ---- peeled last iteration: no prefetch; stores spread over p4..p7 ----
    {
        const int t1 = 2 * (NITER - 1) + 1;

        // p0
        loadA(0, 0); loadB(0, 0);
        stageA(1, 0, t1);
        asm volatile("s_waitcnt lgkmcnt(8)" ::: "memory");
        SB0(); BARR();
        asm volatile("s_waitcnt lgkmcnt(0)" ::: "memory"); SB0();
        mfma16(0, 0);
        SB0(); BARR();

        // p1
        loadB(0, 1);
        stageA(1, 1, t1);
        SB0(); BARR();
        asm volatile("s_waitcnt lgkmcnt(0)" ::: "memory"); SB0();
        mfma16(0, 1);
        SB0(); BARR();

        // p2
        loadA(0, 1);
        SB0(); BARR();
        asm volatile("s_waitcnt lgkmcnt(0)" ::: "memory"); SB0();
        mfma16(1, 0);
        SB0(); BARR();

        // p3: retire buf1 A stages before p4 reads
        SB0(); BARR();
        mfma16(1, 1);
        asm volatile("s_waitcnt vmcnt(0)" ::: "memory");
        SB0(); BARR();

        // p4: final (0,0) -> store it
        loadA(1, 0); loadB(1, 0);
        asm volatile("s_waitcnt lgkmcnt(8)" ::: "memory");
        SB0(); BARR();
        asm volatile("s_waitcnt lgkmcnt(0)" ::: "memory"); SB0();
        mfma16(0, 0);
        storeQuad(0, 0);
        SB0(); BARR();

        // p5: final (0,1)
        loadB(1, 1);
        SB0(); BARR();
        asm volatile("s_waitcnt lgkmcnt(0)" ::: "memory"); SB0();
        mfma16(0, 1);
        storeQuad(0, 1);
        SB0(); BARR();

        // p6: final (1,0)
        loadA(1, 1);
        SB0(); BARR();
        asm volatile("s_waitcnt lgkmcnt(0)" ::: "memory"); SB0();
        mfma16(1, 0);
        storeQuad(1, 0);
        SB0(); BARR();

        // p7: final (1,1)
        SB0(); BARR();
        mfma16(1, 1);
        storeQuad(1, 1);
    }
}

// Fused scan over n-major Pb[z][N][T]: 256 blocks x 512 threads; block owns
// NB_N=16 neurons for ALL t. Waves 0-6 (producers): write out phase ph-1
// spk/mem from ringMem (lane owns 4 consecutive n -> float4 stores). Threads
// 0-255 additionally stage phase ph+1: thread owns (n, 8-t chunk) -> uint4
// load per partial (16B, 256B-contiguous per 16 lanes), f32-sum, 2x float4
// ring writes. Wave 7 (consumer, lanes 0..15): serial recurrence
// ringCur -> ringMem.  [R14 structure, measured residual 27.9us]
template <int NPART>
__global__ __launch_bounds__(512) void scan_kernel(const unsigned short* __restrict__ Pb,
                                                   float* __restrict__ out) {
    __shared__ float ringCur[2][NB_N * TP];   // 16.9 KB
    __shared__ float ringMem[2][NB_N * TP];   // 16.9 KB

    const int tid  = threadIdx.x;
    const int wv   = tid >> 6;     // 0..7
    const int lane = tid & 63;
    const int n0   = blockIdx.x * NB_N;

    const int pn = lane & 15;   // consumer: neuron offset within block

    // staging geometry (threads 0-255)
    const int sn = tid >> 4;    // neuron 0..15
    const int sc = tid & 15;    // 8-t chunk 0..15

    float mem = 0.0f;           // consumer state (wave 7, lanes 0..15)

    auto stage = [&](int buf, size_t tb) {
        float s[8];
#pragma unroll
        for (int j = 0; j < 8; ++j) s[j] = 0.0f;
#pragma unroll
        for (int zz = 0; zz < NPART; ++zz) {
            const uint4 v = *(const uint4*)(Pb + (size_t)zz * TN +
                                            (size_t)(n0 + sn) * T_STEPS + tb + sc * 8);
            unsigned int w0 = v.x, w1 = v.y, w2 = v.z, w3 = v.w;
            s[0] += __builtin_bit_cast(float, w0 << 16);
            s[1] += __builtin_bit_cast(float, w0 & 0xFFFF0000u);
            s[2] += __builtin_bit_cast(float, w1 << 16);
            s[3] += __builtin_bit_cast(float, w1 & 0xFFFF0000u);
            s[4] += __builtin_bit_cast(float, w2 << 16);
            s[5] += __builtin_bit_cast(float, w2 & 0xFFFF0000u);
            s[6] += __builtin_bit_cast(float, w3 << 16);
            s[7] += __builtin_bit_cast(float, w3 & 0xFFFF0000u);
        }
        float4 f0; f0.x = s[0]; f0.y = s[1]; f0.z = s[2]; f0.w = s[3];
        float4 f1; f1.x = s[4]; f1.y = s[5]; f1.z = s[6]; f1.w = s[7];
        float* rc = &ringCur[buf][sn * TP + sc * 8];
        *(float4*)rc = f0;
        *(float4*)(rc + 4) = f1;
    };

    auto writeOut = [&](int buf, size_t tb) {
        const float* mr = ringMem[buf];
        for (int it = tid; it < 512; it += 448) {
            int t  = it >> 2;
            int nq = it & 3;
            float m0 = mr[(nq * 4 + 0) * TP + t];
            float m1 = mr[(nq * 4 + 1) * TP + t];
            float m2 = mr[(nq * 4 + 2) * TP + t];
            float m3 = mr[(nq * 4 + 3) * TP + t];
            float4 mv; mv.x = m0; mv.y = m1; mv.z = m2; mv.w = m3;
            float4 sv;
            sv.x = m0 > 1.0f ? 1.0f : 0.0f;
            sv.y = m1 > 1.0f ? 1.0f : 0.0f;
            sv.z = m2 > 1.0f ? 1.0f : 0.0f;
            sv.w = m3 > 1.0f ? 1.0f : 0.0f;
            size_t idx = (tb + t) * N_OUT + n0 + nq * 4;
            *(float4*)&out[idx]      = sv;
            *(float4*)&out[TN + idx] = mv;
        }
    };

    // ---- prefill: phase 0 -> ringCur[0] ----
    if (tid < 256) stage(0, 0);
    __syncthreads();

    for (int ph = 0; ph < NPH; ++ph) {
        if (wv < 7) {
            if (ph >= 1) writeOut((ph - 1) & 1, (size_t)(ph - 1) * PH_T);
            if (tid < 256 && ph + 1 < NPH)
                stage((ph + 1) & 1, (size_t)(ph + 1) * PH_T);
        } else if (lane < 16) {
            // consumer: 128 serial steps out of ringCur[ph&1]
            const float* base = &ringCur[ph & 1][pn * TP];
            float* mbase = &ringMem[ph & 1][pn * TP];
#pragma unroll
            for (int sub = 0; sub < 4; ++sub) {
                float2 buf[16];
#pragma unroll
                for (int q = 0; q < 16; ++q)
                    buf[q] = *(const float2*)&base[sub * 32 + q * 2];
#pragma unroll
                for (int q = 0; q < 16; ++q) {
                    float rst = mem > 1.0f ? 1.0f : 0.0f;
                    mem = fmaf(0.9f, mem, buf[q].x) - rst;
                    float m0 = mem;
                    rst = mem > 1.0f ? 1.0f : 0.0f;
                    mem = fmaf(0.9f, mem, buf[q].y) - rst;
                    float2 mo; mo.x = m0; mo.y = mem;
                    *(float2*)&mbase[sub * 32 + q * 2] = mo;
                }
            }
        }
        __syncthreads();
    }

    // ---- tail: write out phase NPH-1 ----
    if (wv < 7) writeOut((NPH - 1) & 1, (size_t)(NPH - 1) * PH_T);
}

extern "C" void kernel_launch(void* const* d_in, const int* in_sizes, int n_in,
                              void* d_out, int out_size, void* d_ws, size_t ws_size,
                              hipStream_t stream) {
    const float* x = (const float*)d_in[0];  // [1024][4096] fp32
    const float* W = (const float*)d_in[1];  // [4096][4096] fp32
    float* out = (float*)d_out;              // [2][1024][4096] fp32

    char* ws = (char*)d_ws;
    const size_t xbBytes = (size_t)T_STEPS * N_IN * 2;    // 8 MB
    const size_t WbBytes = (size_t)N_OUT * N_IN * 2;      // 33.6 MB
    const size_t PBytes  = TN * 2;                        // 8.4 MB per bf16 partial
    short* xb = (short*)ws;
    short* Wb = (short*)(ws + xbBytes);
    unsigned short* Pb = (unsigned short*)(ws + xbBytes + WbBytes);

    // Split-K: S=4 -> 256 blocks = 1/CU for the 128KB-LDS 8-phase gemm.
    int S = 1;
    if (ws_size >= xbBytes + WbBytes + 4 * PBytes)      S = 4;
    else if (ws_size >= xbBytes + WbBytes + 2 * PBytes) S = 2;

    {
        const int n4x = T_STEPS * N_IN / 4;
        const int n4w = N_OUT * N_IN / 4;
        const int nthr = n4x + n4w;
        cvt2_kernel<<<(nthr + 255) / 256, 256, 0, stream>>>(
            (const float4*)x, (ushort4*)xb, n4x,
            (const float4*)W, (ushort4*)Wb, n4w);
    }

    gemm8<<<64 * S, 512, 0, stream>>>(xb, Wb, Pb, N_IN / S);

    if (S == 4)      scan_kernel<4><<<N_OUT / NB_N, 512, 0, stream>>>(Pb, out);
    else if (S == 2) scan_kernel<2><<<N_OUT / NB_N, 512, 0, stream>>>(Pb, out);
    else             scan_kernel<1><<<N_OUT / NB_N, 512, 0, stream>>>(Pb, out);
}